// Round 1
// baseline (92.717 us; speedup 1.0000x reference)
//
#include <hip/hip_runtime.h>
#include <stdint.h>

#define T_ 128
#define S_ 512
#define STARTT 126
#define ENDT 127

typedef float f32x4 __attribute__((ext_vector_type(4)));
typedef __bf16 bf16x8 __attribute__((ext_vector_type(8)));

union BFU { unsigned short s[8]; bf16x8 v; };

__device__ __forceinline__ unsigned short bf16r(float f) {
  unsigned int x = __float_as_uint(f);
  x += 0x7fffu + ((x >> 16) & 1u);
  return (unsigned short)(x >> 16);
}

// One block per batch. 8 waves: waves 0-3 run the forward chain, waves 4-7 the
// backward chain; they meet at t=255.  Per step, the 128x128 matvec
// S = E*u is done with 8x mfma_f32_16x16x32_bf16 per chain (A rows broadcast
// to u, so A-row layout is irrelevant; k-mapping cancels between A and B).
__global__ __launch_bounds__(512)
void crf_fused(const float* __restrict__ feats,
               const int* __restrict__ tags,
               const int* __restrict__ mask,
               const float* __restrict__ trans,
               float* __restrict__ out)
{
  const int b    = blockIdx.x;
  const int tid  = threadIdx.x;
  const int lane = tid & 63;
  const int w    = tid >> 6;      // 0..7
  const int dir  = (w >= 4);      // 0 = forward, 1 = backward
  const int wd   = w & 3;         // wave within direction

  __shared__ __align__(16) float tstage[T_ * T_];          // 64 KB staged transitions
  __shared__ float red_s[8];
  __shared__ float red_l[8];
  __shared__ float sc_final;
  __shared__ __align__(16) unsigned short ubuf[2][2][T_];  // [dir][parity][tag], bf16 bits
  __shared__ float h0buf[2][2];
  __shared__ float hfF[T_], hfB[T_];
  __shared__ float cshare[2];

  const float* fb = feats + (size_t)b * (S_ * T_);

  // ---------------- stage transitions into LDS (coalesced) ----------------
  {
    const f32x4* src = (const f32x4*)trans;
    f32x4* dst = (f32x4*)tstage;
    #pragma unroll
    for (int i = 0; i < 8; ++i) dst[tid + 512 * i] = src[tid + 512 * i];
  }
  __syncthreads();

  // ---------------- gold score (one s per thread) ----------------
  {
    int s = tid;
    int cur  = tags[b * S_ + s];
    int prev = (s == 0) ? STARTT : tags[b * S_ + s - 1];
    float mk = (float)mask[b * S_ + s];
    float sc = (tstage[prev * T_ + cur] + fb[s * T_ + cur]) * mk;
    float ln = mk;
    #pragma unroll
    for (int off = 32; off; off >>= 1) {
      sc += __shfl_down(sc, off);
      ln += __shfl_down(ln, off);
    }
    if (lane == 0) { red_s[w] = sc; red_l[w] = ln; }
  }
  __syncthreads();
  if (tid == 0) {
    float sc = 0.f, ln = 0.f;
    #pragma unroll
    for (int i = 0; i < 8; ++i) { sc += red_s[i]; ln += red_l[i]; }
    int L = (int)ln;
    int last = (L == 0) ? STARTT : tags[b * S_ + L - 1];
    sc_final = sc + tstage[last * T_ + ENDT];
  }

  // ---------------- build static E = exp(Tr) MFMA B-fragments ----------------
  // fwd: out n = j (row of Tr), red k = i (col).  bwd: out n = i, red k = j.
  const int n_ = lane & 15;
  const int g_ = lane >> 4;
  bf16x8 Bf0[4], Bf1[4];
  #pragma unroll
  for (int tt = 0; tt < 2; ++tt) {
    #pragma unroll
    for (int c = 0; c < 4; ++c) {
      BFU u_;
      #pragma unroll
      for (int e = 0; e < 8; ++e) {
        int kk = 32 * c + 8 * g_ + e;
        int nn = 16 * (2 * wd + tt) + n_;
        int row = dir ? kk : nn;
        int col = dir ? nn : kk;
        u_.s[e] = bf16r(__expf(tstage[row * T_ + col]));
      }
      if (tt == 0) Bf0[c] = u_.v; else Bf1[c] = u_.v;
    }
  }

  // ---------------- feat prefetch ring (8 rows deep, register slots) ----------------
  const int jf = 32 * wd + (lane & 31);            // this thread's output tag index
  const int rs = dir ? -T_ : T_;                   // row stride (bwd walks down)
  const float* fpD = fb + jf + (dir ? (511 * T_) : 0);
  float f0 = fpD[0];
  float f1 = fpD[1 * rs];
  float f2 = fpD[2 * rs];
  float f3 = fpD[3 * rs];
  float f4 = fpD[4 * rs];
  float f5 = fpD[5 * rs];
  float f6 = fpD[6 * rs];
  float f7 = fpD[7 * rs];

  float Ctot = 0.f;
  float hv;

  // ---------------- peel step k=0 ----------------
  if (!dir) {
    float tv = tstage[jf * T_ + STARTT];           // Tr[j, START]
    hv = f0 + fmaxf(tv, -69.0f);                   // alpha_0[j]
  } else {
    hv = 0.f;                                      // beta_511 = 0
  }
  {
    float uu = __expf(dir ? (hv + f0) : hv);
    if (lane < 32) ubuf[dir][1][jf] = bf16r(uu);
    if (lane == 0 && wd == 0) h0buf[dir][1] = 0.f;
  }
  f0 = fpD[8 * rs];                                // refill slot 0
  asm volatile("s_waitcnt lgkmcnt(0)" ::: "memory");
  __builtin_amdgcn_s_barrier();

  // ---------------- main recursion ----------------
#define CRF_STEP(KK, FR) do {                                                  \
    const int par_ = (KK) & 1;                                                 \
    float h0p = h0buf[dir][par_];                                              \
    const unsigned short* ub_ = &ubuf[dir][par_][0];                           \
    bf16x8 A0 = *(const bf16x8*)(ub_ +       8 * g_);                          \
    bf16x8 A1 = *(const bf16x8*)(ub_ + 32 +  8 * g_);                          \
    bf16x8 A2 = *(const bf16x8*)(ub_ + 64 +  8 * g_);                          \
    bf16x8 A3 = *(const bf16x8*)(ub_ + 96 +  8 * g_);                          \
    f32x4 ac0 = {0.f, 0.f, 0.f, 0.f};                                          \
    f32x4 ac1 = ac0, ac2 = ac0, ac3 = ac0;                                     \
    ac0 = __builtin_amdgcn_mfma_f32_16x16x32_bf16(A0, Bf0[0], ac0, 0, 0, 0);   \
    ac2 = __builtin_amdgcn_mfma_f32_16x16x32_bf16(A0, Bf1[0], ac2, 0, 0, 0);   \
    ac1 = __builtin_amdgcn_mfma_f32_16x16x32_bf16(A1, Bf0[1], ac1, 0, 0, 0);   \
    ac3 = __builtin_amdgcn_mfma_f32_16x16x32_bf16(A1, Bf1[1], ac3, 0, 0, 0);   \
    ac0 = __builtin_amdgcn_mfma_f32_16x16x32_bf16(A2, Bf0[2], ac0, 0, 0, 0);   \
    ac2 = __builtin_amdgcn_mfma_f32_16x16x32_bf16(A2, Bf1[2], ac2, 0, 0, 0);   \
    ac1 = __builtin_amdgcn_mfma_f32_16x16x32_bf16(A3, Bf0[3], ac1, 0, 0, 0);   \
    ac3 = __builtin_amdgcn_mfma_f32_16x16x32_bf16(A3, Bf1[3], ac3, 0, 0, 0);   \
    float Sv = (lane & 16) ? (ac2[0] + ac3[0]) : (ac0[0] + ac1[0]);            \
    Sv = fmaxf(Sv, 1e-30f);                                                    \
    float lg_ = __logf(Sv) - h0p;                                              \
    hv = dir ? lg_ : ((FR) + lg_);                                             \
    Ctot += h0p;                                                               \
    float uu_ = __expf(dir ? (hv + (FR)) : hv);                                \
    if (lane < 32) ubuf[dir][par_ ^ 1][jf] = bf16r(uu_);                       \
    if (lane == 0 && wd == 0) h0buf[dir][par_ ^ 1] = hv;                       \
    if ((KK) + 8 <= 255) FR = fpD[((KK) + 8) * rs];                            \
    asm volatile("s_waitcnt lgkmcnt(0)" ::: "memory");                         \
    __builtin_amdgcn_s_barrier();                                              \
} while (0)

  #pragma unroll 1
  for (int k0 = 1; k0 <= 241; k0 += 8) {
    CRF_STEP(k0 + 0, f1); CRF_STEP(k0 + 1, f2); CRF_STEP(k0 + 2, f3); CRF_STEP(k0 + 3, f4);
    CRF_STEP(k0 + 4, f5); CRF_STEP(k0 + 5, f6); CRF_STEP(k0 + 6, f7); CRF_STEP(k0 + 7, f0);
  }
  CRF_STEP(249, f1); CRF_STEP(250, f2); CRF_STEP(251, f3); CRF_STEP(252, f4);
  CRF_STEP(253, f5); CRF_STEP(254, f6); CRF_STEP(255, f7);

  // ---------------- extra backward-only step k=256 (produces beta_255) ----------------
  if (dir) {
    float h0p = h0buf[1][0];
    const unsigned short* ub_ = &ubuf[1][0][0];
    bf16x8 A0 = *(const bf16x8*)(ub_ +       8 * g_);
    bf16x8 A1 = *(const bf16x8*)(ub_ + 32 +  8 * g_);
    bf16x8 A2 = *(const bf16x8*)(ub_ + 64 +  8 * g_);
    bf16x8 A3 = *(const bf16x8*)(ub_ + 96 +  8 * g_);
    f32x4 ac0 = {0.f, 0.f, 0.f, 0.f};
    f32x4 ac1 = ac0, ac2 = ac0, ac3 = ac0;
    ac0 = __builtin_amdgcn_mfma_f32_16x16x32_bf16(A0, Bf0[0], ac0, 0, 0, 0);
    ac2 = __builtin_amdgcn_mfma_f32_16x16x32_bf16(A0, Bf1[0], ac2, 0, 0, 0);
    ac1 = __builtin_amdgcn_mfma_f32_16x16x32_bf16(A1, Bf0[1], ac1, 0, 0, 0);
    ac3 = __builtin_amdgcn_mfma_f32_16x16x32_bf16(A1, Bf1[1], ac3, 0, 0, 0);
    ac0 = __builtin_amdgcn_mfma_f32_16x16x32_bf16(A2, Bf0[2], ac0, 0, 0, 0);
    ac2 = __builtin_amdgcn_mfma_f32_16x16x32_bf16(A2, Bf1[2], ac2, 0, 0, 0);
    ac1 = __builtin_amdgcn_mfma_f32_16x16x32_bf16(A3, Bf0[3], ac1, 0, 0, 0);
    ac3 = __builtin_amdgcn_mfma_f32_16x16x32_bf16(A3, Bf1[3], ac3, 0, 0, 0);
    float Sv = (lane & 16) ? (ac2[0] + ac3[0]) : (ac0[0] + ac1[0]);
    Sv = fmaxf(Sv, 1e-30f);
    hv = __logf(Sv) - h0p;
    Ctot += h0p;
  }

  // ---------------- meet: logZ = CtotF + CtotB + LSE_i(hF_i + hB_i) - 10000 ----------------
  if (lane < 32) {
    if (!dir) hfF[jf] = hv; else hfB[jf] = hv;
  }
  if (tid == 0)   cshare[0] = Ctot;
  if (tid == 256) cshare[1] = Ctot;
  __syncthreads();
  if (tid < 64) {
    float a  = hfF[tid]      + hfB[tid];
    float b2 = hfF[tid + 64] + hfB[tid + 64];
    float M = fmaxf(a, b2);
    #pragma unroll
    for (int off = 32; off; off >>= 1) M = fmaxf(M, __shfl_xor(M, off));
    float sm = __expf(a - M) + __expf(b2 - M);
    #pragma unroll
    for (int off = 32; off; off >>= 1) sm += __shfl_xor(sm, off);
    if (tid == 0) {
      float logz = cshare[0] + cshare[1] + M + __logf(sm) - 10000.0f;
      out[b] = logz - sc_final;
    }
  }
#undef CRF_STEP
}

extern "C" void kernel_launch(void* const* d_in, const int* in_sizes, int n_in,
                              void* d_out, int out_size, void* d_ws, size_t ws_size,
                              hipStream_t stream) {
  const float* feats = (const float*)d_in[0];
  const int*   tags  = (const int*)d_in[1];
  const int*   mask  = (const int*)d_in[2];
  const float* trans = (const float*)d_in[3];
  float* out = (float*)d_out;
  hipLaunchKernelGGL(crf_fused, dim3(256), dim3(512), 0, stream,
                     feats, tags, mask, trans, out);
}